// Round 8
// baseline (729.173 us; speedup 1.0000x reference)
//
#include <hip/hip_runtime.h>
#include <hip/hip_bf16.h>

#define NEG_SLOPE 0.2f
#define IN_DIM 256
#define C1 64
#define C2 32
#define ODIM 40
#define SCAN_CHUNK 4096   // 256 threads * 16 items
#define BSHIFT 12         // bucket = dst >> 12 (4096 nodes/bucket)
#define ECHUNK 8192       // edges per block in bucket passes

// ---------------- CSR build (bucketed two-level counting sort) ----------------

__global__ void k_init_cnt(int* cnt, int n) {
    int i = blockIdx.x * 256 + threadIdx.x;
    if (i < n) cnt[i] = 1;  // start at 1: self-loop
}

// per-block bucket histogram -> gh[bucket][block]
__global__ void k_bhist(const int* __restrict__ dst, int E, int* __restrict__ gh,
                        int nblk, int nb) {
    __shared__ int h[32];
    int t = threadIdx.x;
    if (t < 32) h[t] = 0;
    __syncthreads();
    int base = blockIdx.x * ECHUNK;
    int end = min(base + ECHUNK, E);
    for (int i = base + t; i < end; i += 256) atomicAdd(&h[dst[i] >> BSHIFT], 1);
    __syncthreads();
    if (t < nb) gh[t * nblk + blockIdx.x] = h[t];
}

// flat exclusive scan of gh (bucket-major), single block
__global__ void k_bscan(int* __restrict__ gh, int L) {
    __shared__ int lds[256];
    __shared__ int carry;
    int t = threadIdx.x;
    if (t == 0) carry = 0;
    __syncthreads();
    for (int base = 0; base < L; base += 256) {
        int v = (base + t < L) ? gh[base + t] : 0;
        lds[t] = v; __syncthreads();
        for (int off = 1; off < 256; off <<= 1) {
            int u = (t >= off) ? lds[t - off] : 0;
            __syncthreads();
            lds[t] += u;
            __syncthreads();
        }
        if (base + t < L) gh[base + t] = lds[t] - v + carry;  // exclusive + carry
        __syncthreads();
        if (t == 0) carry += lds[255];
        __syncthreads();
    }
}

// place edges into bucket-ordered pairs arrays (no global atomics; LDS cursors)
__global__ void k_bplace(const int* __restrict__ src, const int* __restrict__ dst, int E,
                         const int* __restrict__ gh, int nblk, int nb,
                         int* __restrict__ psrc, int* __restrict__ pdst) {
    __shared__ int cur[32];
    int t = threadIdx.x;
    if (t < nb) cur[t] = gh[t * nblk + blockIdx.x];
    __syncthreads();
    int base = blockIdx.x * ECHUNK;
    int end = min(base + ECHUNK, E);
    for (int i = base + t; i < end; i += 256) {
        int d = dst[i];
        int pos = atomicAdd(&cur[d >> BSHIFT], 1);
        psrc[pos] = src[i];
        pdst[pos] = d;
    }
}

// per-node degree count over bucket-ordered dst.
// XCD-swizzled: XCD x (= blockIdx%8) gets contiguous chunk slice -> atomics stay
// in a small L2-hot cnt window per XCD.
__global__ void k_count2(const int* __restrict__ pdst, int E, int* __restrict__ cnt, int q) {
    int chunk = (blockIdx.x & 7) * q + (blockIdx.x >> 3);
    int i = chunk * 256 + threadIdx.x;
    if (i < E) atomicAdd(&cnt[pdst[i]], 1);
}

__global__ void k_scan1(const int* __restrict__ cnt, int n, int* __restrict__ bsums) {
    __shared__ int lds[256];
    int t = threadIdx.x;
    int base = blockIdx.x * SCAN_CHUNK + t * 16;
    int s = 0;
#pragma unroll
    for (int i = 0; i < 16; i++) { int idx = base + i; s += (idx < n) ? cnt[idx] : 0; }
    lds[t] = s; __syncthreads();
    for (int off = 128; off > 0; off >>= 1) {
        if (t < off) lds[t] += lds[t + off];
        __syncthreads();
    }
    if (t == 0) bsums[blockIdx.x] = lds[0];
}

__global__ void k_scan2(int* bsums, int nb, int* row_ptr, int n, int total) {
    __shared__ int lds[256];
    int t = threadIdx.x;
    int v = (t < nb) ? bsums[t] : 0;
    lds[t] = v; __syncthreads();
    for (int off = 1; off < 256; off <<= 1) {
        int u = (t >= off) ? lds[t - off] : 0;
        __syncthreads();
        lds[t] += u;
        __syncthreads();
    }
    if (t < nb) bsums[t] = lds[t] - v;  // exclusive
    if (t == 0) row_ptr[n] = total;
}

__global__ void k_scan3(const int* __restrict__ cnt, int n, const int* __restrict__ bsums,
                        int* __restrict__ row_ptr) {
    __shared__ int lds[256];
    int t = threadIdx.x;
    int base = blockIdx.x * SCAN_CHUNK + t * 16;
    int loc[16];
    int s = 0;
#pragma unroll
    for (int i = 0; i < 16; i++) {
        int idx = base + i;
        int c = (idx < n) ? cnt[idx] : 0;
        loc[i] = s; s += c;
    }
    lds[t] = s; __syncthreads();
    for (int off = 1; off < 256; off <<= 1) {
        int u = (t >= off) ? lds[t - off] : 0;
        __syncthreads();
        lds[t] += u;
        __syncthreads();
    }
    int texcl = lds[t] - s + bsums[blockIdx.x];
#pragma unroll
    for (int i = 0; i < 16; i++) {
        int idx = base + i;
        if (idx < n) row_ptr[idx] = texcl + loc[i];
    }
}

__global__ void k_selfloop(const int* __restrict__ row_ptr, int n, int* __restrict__ adj,
                           int* __restrict__ cnt) {
    int i = blockIdx.x * 256 + threadIdx.x;
    if (i < n) { adj[row_ptr[i]] = i; cnt[i] = 1; }
}

// final scatter over bucket-ordered pairs; XCD-swizzled so each XCD's adj
// write window (~1.6MB) stays resident in its own L2 -> one writeback per line.
__global__ void k_adj2(const int* __restrict__ psrc, const int* __restrict__ pdst, int E,
                       const int* __restrict__ row_ptr, int* __restrict__ cnt,
                       int* __restrict__ adj, int q) {
    int chunk = (blockIdx.x & 7) * q + (blockIdx.x >> 3);
    int i = chunk * 256 + threadIdx.x;
    if (i < E) {
        int d = pdst[i];
        int pos = row_ptr[d] + atomicAdd(&cnt[d], 1);
        adj[pos] = psrc[i];
    }
}

// ---------------- GEMM1: h1 = x @ W1 ----------------
// lane = row (coalesced x loads); block-uniform column half -> W1 via SGPR loads.

__global__ __launch_bounds__(256, 4)
void k_gemm1(const float* __restrict__ x, const float* __restrict__ W1,
             float* __restrict__ h1, int n) {
    int t = threadIdx.x;
    int wave = t >> 6, lane = t & 63;
    int chalf = (blockIdx.x & 1) * 32;                  // block-uniform column half
    int row = (blockIdx.x >> 1) * 256 + wave * 64 + lane;
    bool active = row < n;
    int rowc = active ? row : n - 1;
    const float4* xr = (const float4*)(x + (size_t)rowc * IN_DIM);

    float acc[32];
#pragma unroll
    for (int c = 0; c < 32; c++) acc[c] = 0.f;

#define FMA_K(XC, KK) { \
        const float* wk = wb + (KK) * C1; \
        _Pragma("unroll") \
        for (int c = 0; c < 32; c++) acc[c] = fmaf((XC), wk[c], acc[c]); }

    for (int k0 = 0; k0 < 16; k0++) {                   // BK = 16
        float4 xv0 = xr[k0 * 4 + 0];
        float4 xv1 = xr[k0 * 4 + 1];
        float4 xv2 = xr[k0 * 4 + 2];
        float4 xv3 = xr[k0 * 4 + 3];
        const float* wb = W1 + (size_t)(k0 * 16) * C1 + chalf;  // uniform
        FMA_K(xv0.x, 0)  FMA_K(xv0.y, 1)  FMA_K(xv0.z, 2)  FMA_K(xv0.w, 3)
        FMA_K(xv1.x, 4)  FMA_K(xv1.y, 5)  FMA_K(xv1.z, 6)  FMA_K(xv1.w, 7)
        FMA_K(xv2.x, 8)  FMA_K(xv2.y, 9)  FMA_K(xv2.z, 10) FMA_K(xv2.w, 11)
        FMA_K(xv3.x, 12) FMA_K(xv3.y, 13) FMA_K(xv3.z, 14) FMA_K(xv3.w, 15)
    }
#undef FMA_K

    if (!active) return;
    float* hp = h1 + (size_t)row * C1 + chalf;
#pragma unroll
    for (int j = 0; j < 8; j++)
        *(float4*)(hp + j * 4) =
            make_float4(acc[j * 4], acc[j * 4 + 1], acc[j * 4 + 2], acc[j * 4 + 3]);
}

// ---------------- alpha_src / alpha_dst for layer 1 (wave per row) ----------------

__global__ __launch_bounds__(256)
void k_alpha(const float* __restrict__ h, const float* __restrict__ attS,
             const float* __restrict__ attD, float* __restrict__ as_,
             float* __restrict__ ad_, int n) {
    int wave = (blockIdx.x * 256 + threadIdx.x) >> 6;
    int lane = threadIdx.x & 63;
    if (wave >= n) return;
    float hv = h[(size_t)wave * C1 + lane];
    float vs = hv * attS[lane], vd = hv * attD[lane];
#pragma unroll
    for (int off = 32; off > 0; off >>= 1) {
        vs += __shfl_xor(vs, off);
        vd += __shfl_xor(vd, off);
    }
    if (lane == 0) { as_[wave] = vs; ad_[wave] = vd; }
}

// ---------------- Layer-1 aggregation: one wave per dst node, lane = channel ----------------

__global__ __launch_bounds__(256)
void k_agg1(const float* __restrict__ h1, const float* __restrict__ as1,
            const float* __restrict__ ad1, const int* __restrict__ row_ptr,
            const int* __restrict__ adj, const float* __restrict__ b1,
            float* __restrict__ h1out, int n) {
    int wave = (blockIdx.x * 256 + threadIdx.x) >> 6;
    int lane = threadIdx.x & 63;
    if (wave >= n) return;
    int d = wave;
    int beg = row_ptr[d], end = row_ptr[d + 1];
    float adv = ad1[d];
    float acc = 0.f, dsum = 0.f;
    for (int base = beg; base < end; base += 64) {
        int cnt = min(64, end - base);
        int s = d; float w = 0.f;
        if (lane < cnt) {
            s = adj[base + lane];
            float lg = as1[s] + adv;
            lg = lg > 0.f ? lg : NEG_SLOPE * lg;
            w = expf(lg);
            dsum += w;
        }
        int j = 0;
        for (; j + 4 <= cnt; j += 4) {
            int s0 = __shfl(s, j),     s1 = __shfl(s, j + 1);
            int s2 = __shfl(s, j + 2), s3 = __shfl(s, j + 3);
            float w0 = __shfl(w, j),     w1 = __shfl(w, j + 1);
            float w2 = __shfl(w, j + 2), w3 = __shfl(w, j + 3);
            float g0 = h1[(size_t)s0 * C1 + lane];
            float g1 = h1[(size_t)s1 * C1 + lane];
            float g2 = h1[(size_t)s2 * C1 + lane];
            float g3 = h1[(size_t)s3 * C1 + lane];
            acc = fmaf(w0, g0, acc); acc = fmaf(w1, g1, acc);
            acc = fmaf(w2, g2, acc); acc = fmaf(w3, g3, acc);
        }
        for (; j < cnt; j++) {
            int sj = __shfl(s, j);
            float wj = __shfl(w, j);
            acc = fmaf(wj, h1[(size_t)sj * C1 + lane], acc);
        }
    }
#pragma unroll
    for (int off = 32; off > 0; off >>= 1) dsum += __shfl_xor(dsum, off);
    float out = acc / dsum + b1[lane];
    h1out[(size_t)d * C1 + lane] = out > 0.f ? out : 0.f;
}

// ---------------- GEMM2 + alpha2 ----------------

__global__ __launch_bounds__(256)
void k_gemm2(const float* __restrict__ h1out, const float* __restrict__ W2,
             const float* __restrict__ attS, const float* __restrict__ attD,
             float* __restrict__ h2, float* __restrict__ as2, float* __restrict__ ad2, int n) {
    __shared__ float w2t[C2 * 68];
    __shared__ float sAttS[C2], sAttD[C2];
    int t = threadIdx.x;
    for (int i = t; i < C1 * C2; i += 256) {
        int k = i >> 5, c = i & 31;
        w2t[c * 68 + k] = W2[i];
    }
    if (t < C2) { sAttS[t] = attS[t]; sAttD[t] = attD[t]; }
    __syncthreads();
    int wave = t >> 6, lane = t & 63;
    int col = lane & 31, half = lane >> 5;
    int rowbase = blockIdx.x * 32 + wave * 8;
    const float* wrow = &w2t[col * 68];
    for (int rr = 0; rr < 8; rr += 2) {
        int row = rowbase + rr + half;
        if (row >= n) return;
        float acc = 0.f;
#pragma unroll
        for (int k = 0; k < C1; k += 4) {
            float4 wv = *(const float4*)&wrow[k];
            float4 xv = *(const float4*)&h1out[(size_t)row * C1 + k];
            acc = fmaf(xv.x, wv.x, acc);
            acc = fmaf(xv.y, wv.y, acc);
            acc = fmaf(xv.z, wv.z, acc);
            acc = fmaf(xv.w, wv.w, acc);
        }
        h2[(size_t)row * C2 + col] = acc;
        float vs = acc * sAttS[col], vd = acc * sAttD[col];
#pragma unroll
        for (int off = 16; off > 0; off >>= 1) {
            vs += __shfl_xor(vs, off);
            vd += __shfl_xor(vd, off);
        }
        if (col == 0) { as2[row] = vs; ad2[row] = vd; }
    }
}

// ---------------- Layer-2 aggregation + bias + relu -> emb (d_out) ----------------

__global__ __launch_bounds__(256)
void k_agg2(const float* __restrict__ h2, const float* __restrict__ as2,
            const float* __restrict__ ad2, const int* __restrict__ row_ptr,
            const int* __restrict__ adj, const float* __restrict__ b2,
            float* __restrict__ emb, int n) {
    int wave = (blockIdx.x * 256 + threadIdx.x) >> 6;
    int lane = threadIdx.x & 63;
    if (wave >= n) return;
    int d = wave;
    int beg = row_ptr[d], end = row_ptr[d + 1];
    float adv = ad2[d];
    int c = lane & 31, half = lane >> 5;
    float acc = 0.f, dsum = 0.f;
    for (int base = beg; base < end; base += 64) {
        int cnt = min(64, end - base);
        int s = d; float w = 0.f;
        if (lane < cnt) {
            s = adj[base + lane];
            float lg = as2[s] + adv;
            lg = lg > 0.f ? lg : NEG_SLOPE * lg;
            w = expf(lg);
            dsum += w;
        }
        int j = 0;
        for (; j + 4 <= cnt; j += 4) {
            int sa = __shfl(s, j + half);
            int sb = __shfl(s, j + 2 + half);
            float wa = __shfl(w, j + half);
            float wb = __shfl(w, j + 2 + half);
            float ga = h2[(size_t)sa * C2 + c];
            float gb = h2[(size_t)sb * C2 + c];
            acc = fmaf(wa, ga, acc);
            acc = fmaf(wb, gb, acc);
        }
        for (; j + 2 <= cnt; j += 2) {
            int sj = __shfl(s, j + half);
            float wj = __shfl(w, j + half);
            acc = fmaf(wj, h2[(size_t)sj * C2 + c], acc);
        }
        if (j < cnt) {  // single leftover edge: half 0 only
            int sj = __shfl(s, j);
            float wj = __shfl(w, j);
            if (half == 0) acc = fmaf(wj, h2[(size_t)sj * C2 + c], acc);
        }
    }
    acc += __shfl_xor(acc, 32);
#pragma unroll
    for (int off = 32; off > 0; off >>= 1) dsum += __shfl_xor(dsum, off);
    if (half == 0) {
        float v = acc / dsum + b2[c];
        emb[(size_t)d * C2 + c] = v > 0.f ? v : 0.f;
    }
}

// ---------------- logits = emb @ fcW + fcb ----------------

__global__ __launch_bounds__(256)
void k_logits(const float* __restrict__ emb, const float* __restrict__ fcW,
              const float* __restrict__ fcb, float* __restrict__ out, int n) {
    __shared__ float w[C2 * ODIM];
    __shared__ float b[ODIM];
    int t = threadIdx.x;
    for (int i = t; i < C2 * ODIM; i += 256) w[i] = fcW[i];
    if (t < ODIM) b[t] = fcb[t];
    __syncthreads();
    int lane = t & 63;
    int row = blockIdx.x * 4 + (t >> 6);
    if (row >= n) return;
    float acc = (lane < ODIM) ? b[lane] : 0.f;
    const float4* er = (const float4*)&emb[(size_t)row * C2];
#pragma unroll
    for (int c4 = 0; c4 < 8; c4++) {
        float4 e = er[c4];
        int c = c4 * 4;
        if (lane < ODIM) {
            acc = fmaf(e.x, w[(c + 0) * ODIM + lane], acc);
            acc = fmaf(e.y, w[(c + 1) * ODIM + lane], acc);
            acc = fmaf(e.z, w[(c + 2) * ODIM + lane], acc);
            acc = fmaf(e.w, w[(c + 3) * ODIM + lane], acc);
        }
    }
    if (lane < ODIM) out[(size_t)row * ODIM + lane] = acc;
}

// ---------------- launch ----------------

extern "C" void kernel_launch(void* const* d_in, const int* in_sizes, int n_in,
                              void* d_out, int out_size, void* d_ws, size_t ws_size,
                              hipStream_t stream) {
    const float* x    = (const float*)d_in[0];
    const int*   ei   = (const int*)d_in[1];
    const float* W1   = (const float*)d_in[2];
    const float* aS1  = (const float*)d_in[3];
    const float* aD1  = (const float*)d_in[4];
    const float* b1   = (const float*)d_in[5];
    const float* W2   = (const float*)d_in[6];
    const float* aS2  = (const float*)d_in[7];
    const float* aD2  = (const float*)d_in[8];
    const float* b2   = (const float*)d_in[9];
    const float* fcW  = (const float*)d_in[10];
    const float* fcb  = (const float*)d_in[11];

    const int N = in_sizes[0] / IN_DIM;
    const int E = in_sizes[1] / 2;
    const int* src = ei;
    const int* dst = ei + E;

    // workspace layout (floats/ints)
    float* h1    = (float*)d_ws;               // N*64
    float* h1out = h1 + (size_t)N * C1;        // N*64  (aliased by psrc/pdst pre-agg1)
    float* as1   = h1out + (size_t)N * C1;     // N
    float* ad1   = as1 + N;
    float* as2   = ad1 + N;
    float* ad2   = as2 + N;
    int*   cnt   = (int*)(ad2 + N);            // N
    int*   row_ptr = cnt + N;                  // N+1
    int*   bsums   = row_ptr + (N + 1);        // <=256
    int*   adj     = bsums + 256;              // E+N
    int*   gh      = adj + (E + N);            // nb*nblkE (<16K)
    float* h2    = h1;                         // alias: h1 dead after k_agg1

    // pairs arrays alias h1out (2*E ints = N*64 floats exactly); dead after k_adj2
    int* psrc = (int*)h1out;                   // E
    int* pdst = psrc + E;                      // E

    float* emb    = (float*)d_out;             // N*32
    float* logits = emb + (size_t)N * C2;      // N*40

    int nbN   = (N + 255) / 256;
    int nbS   = (N + SCAN_CHUNK - 1) / SCAN_CHUNK;  // 25
    int nblkE = (E + ECHUNK - 1) / ECHUNK;          // ~391
    int nb    = (N + (1 << BSHIFT) - 1) >> BSHIFT;  // ~25 buckets

    // XCD-swizzled edge-chunk geometry (256 edges/chunk, 8 XCDs)
    int nch   = (E + 255) / 256;
    int nchP  = ((nch + 7) / 8) * 8;
    int q     = nchP / 8;

    // CSR build
    k_init_cnt<<<nbN, 256, 0, stream>>>(cnt, N);
    k_bhist<<<nblkE, 256, 0, stream>>>(dst, E, gh, nblkE, nb);
    k_bscan<<<1, 256, 0, stream>>>(gh, nb * nblkE);
    k_bplace<<<nblkE, 256, 0, stream>>>(src, dst, E, gh, nblkE, nb, psrc, pdst);
    k_count2<<<nchP, 256, 0, stream>>>(pdst, E, cnt, q);
    k_scan1<<<nbS, 256, 0, stream>>>(cnt, N, bsums);
    k_scan2<<<1, 256, 0, stream>>>(bsums, nbS, row_ptr, N, E + N);
    k_scan3<<<nbS, 256, 0, stream>>>(cnt, N, bsums, row_ptr);
    k_selfloop<<<nbN, 256, 0, stream>>>(row_ptr, N, adj, cnt);
    k_adj2<<<nchP, 256, 0, stream>>>(psrc, pdst, E, row_ptr, cnt, adj, q);

    // GAT layers
    int nbG1 = 2 * ((N + 255) / 256);   // x2: column halves
    k_gemm1<<<nbG1, 256, 0, stream>>>(x, W1, h1, N);
    int nbA = (N + 3) / 4;
    k_alpha<<<nbA, 256, 0, stream>>>(h1, aS1, aD1, as1, ad1, N);
    k_agg1<<<nbA, 256, 0, stream>>>(h1, as1, ad1, row_ptr, adj, b1, h1out, N);
    int nbG2 = (N + 31) / 32;
    k_gemm2<<<nbG2, 256, 0, stream>>>(h1out, W2, aS2, aD2, h2, as2, ad2, N);
    k_agg2<<<nbA, 256, 0, stream>>>(h2, as2, ad2, row_ptr, adj, b2, emb, N);
    k_logits<<<nbA, 256, 0, stream>>>(emb, fcW, fcb, logits, N);
}

// Round 9
// 469.668 us; speedup vs baseline: 1.5525x; 1.5525x over previous
//
#include <hip/hip_runtime.h>
#include <hip/hip_bf16.h>

#define NEG_SLOPE 0.2f
#define IN_DIM 256
#define C1 64
#define C2 32
#define ODIM 40
#define SCAN_CHUNK 4096   // 256 threads * 16 items
#define BSHIFT 12         // bucket = dst >> 12 (4096 nodes/bucket)
#define ECHUNK 8192       // edges per block in bucket passes
#define ECH2 16384        // edges per (bucket,chunk) block in node passes
#define CH 10             // max chunks per bucket (131K avg edges/bucket << CH*ECH2)

// ---------------- CSR build: bucket sort, then in-bucket counting sort ----------------

// per-block bucket histogram -> gh[bucket][block]
__global__ void k_bhist(const int* __restrict__ dst, int E, int* __restrict__ gh,
                        int nblk, int nb) {
    __shared__ int h[32];
    int t = threadIdx.x;
    if (t < 32) h[t] = 0;
    __syncthreads();
    int base = blockIdx.x * ECHUNK;
    int end = min(base + ECHUNK, E);
    for (int i = base + t; i < end; i += 256) atomicAdd(&h[dst[i] >> BSHIFT], 1);
    __syncthreads();
    if (t < nb) gh[t * nblk + blockIdx.x] = h[t];
}

// flat exclusive scan of gh (bucket-major), single block
__global__ void k_bscan(int* __restrict__ gh, int L) {
    __shared__ int lds[256];
    __shared__ int carry;
    int t = threadIdx.x;
    if (t == 0) carry = 0;
    __syncthreads();
    for (int base = 0; base < L; base += 256) {
        int v = (base + t < L) ? gh[base + t] : 0;
        lds[t] = v; __syncthreads();
        for (int off = 1; off < 256; off <<= 1) {
            int u = (t >= off) ? lds[t - off] : 0;
            __syncthreads();
            lds[t] += u;
            __syncthreads();
        }
        if (base + t < L) gh[base + t] = lds[t] - v + carry;  // exclusive + carry
        __syncthreads();
        if (t == 0) carry += lds[255];
        __syncthreads();
    }
}

// place edges into bucket-ordered int2 pairs (LDS cursors, no global atomics)
__global__ void k_bplace(const int* __restrict__ src, const int* __restrict__ dst, int E,
                         const int* __restrict__ gh, int nblk, int nb,
                         int2* __restrict__ pairs) {
    __shared__ int cur[32];
    int t = threadIdx.x;
    if (t < nb) cur[t] = gh[t * nblk + blockIdx.x];
    __syncthreads();
    int base = blockIdx.x * ECHUNK;
    int end = min(base + ECHUNK, E);
    for (int i = base + t; i < end; i += 256) {
        int d = dst[i];
        int pos = atomicAdd(&cur[d >> BSHIFT], 1);
        pairs[pos] = make_int2(src[i], d);
    }
}

// block -> (bucket, chunk): xcd-pinned (b & 7 == blockIdx % 8) for L2 locality
__device__ __forceinline__ void bc_map(int blk, int* b, int* c) {
    int xcd = blk & 7, k = blk >> 3;
    *b = (k & 3) * 8 + xcd;
    *c = k >> 2;
}

// per-(bucket,chunk) node-level LDS histogram -> chist[b][c][4096]
__global__ __launch_bounds__(512)
void k_nhist(const int2* __restrict__ pairs, const int* __restrict__ gh, int nblk,
             int nb, int E, int* __restrict__ chist) {
    __shared__ int h[4096];
    int b, c; bc_map(blockIdx.x, &b, &c);
    if (b >= nb) return;
    for (int i = threadIdx.x; i < 4096; i += 512) h[i] = 0;
    __syncthreads();
    int estart = gh[b * nblk];
    int eend = (b + 1 < nb) ? gh[(b + 1) * nblk] : E;
    int s0 = estart + c * ECH2;
    int s1 = min(s0 + ECH2, eend);
    for (int i = s0 + threadIdx.x; i < s1; i += 512)
        atomicAdd(&h[pairs[i].y & 4095], 1);
    __syncthreads();
    int* out = chist + ((size_t)b * CH + c) * 4096;
    for (int i = threadIdx.x; i < 4096; i += 512) out[i] = h[i];
}

// cnt[i] = 1 (self-loop) + sum over chunks; coalesced, no atomics
__global__ void k_cnt(const int* __restrict__ chist, int* __restrict__ cnt, int n) {
    int i = blockIdx.x * 256 + threadIdx.x;
    if (i >= n) return;
    int b = i >> BSHIFT, j = i & 4095;
    const int* p = chist + ((size_t)b * CH) * 4096 + j;
    int s = 1;
#pragma unroll
    for (int c = 0; c < CH; c++) s += p[c * 4096];
    cnt[i] = s;
}

__global__ void k_scan1(const int* __restrict__ cnt, int n, int* __restrict__ bsums) {
    __shared__ int lds[256];
    int t = threadIdx.x;
    int base = blockIdx.x * SCAN_CHUNK + t * 16;
    int s = 0;
#pragma unroll
    for (int i = 0; i < 16; i++) { int idx = base + i; s += (idx < n) ? cnt[idx] : 0; }
    lds[t] = s; __syncthreads();
    for (int off = 128; off > 0; off >>= 1) {
        if (t < off) lds[t] += lds[t + off];
        __syncthreads();
    }
    if (t == 0) bsums[blockIdx.x] = lds[0];
}

__global__ void k_scan2(int* bsums, int nb, int* row_ptr, int n, int total) {
    __shared__ int lds[256];
    int t = threadIdx.x;
    int v = (t < nb) ? bsums[t] : 0;
    lds[t] = v; __syncthreads();
    for (int off = 1; off < 256; off <<= 1) {
        int u = (t >= off) ? lds[t - off] : 0;
        __syncthreads();
        lds[t] += u;
        __syncthreads();
    }
    if (t < nb) bsums[t] = lds[t] - v;  // exclusive
    if (t == 0) row_ptr[n] = total;
}

__global__ void k_scan3(const int* __restrict__ cnt, int n, const int* __restrict__ bsums,
                        int* __restrict__ row_ptr) {
    __shared__ int lds[256];
    int t = threadIdx.x;
    int base = blockIdx.x * SCAN_CHUNK + t * 16;
    int loc[16];
    int s = 0;
#pragma unroll
    for (int i = 0; i < 16; i++) {
        int idx = base + i;
        int c = (idx < n) ? cnt[idx] : 0;
        loc[i] = s; s += c;
    }
    lds[t] = s; __syncthreads();
    for (int off = 1; off < 256; off <<= 1) {
        int u = (t >= off) ? lds[t - off] : 0;
        __syncthreads();
        lds[t] += u;
        __syncthreads();
    }
    int texcl = lds[t] - s + bsums[blockIdx.x];
#pragma unroll
    for (int i = 0; i < 16; i++) {
        int idx = base + i;
        if (idx < n) row_ptr[idx] = texcl + loc[i];
    }
}

__global__ void k_selfloop(const int* __restrict__ row_ptr, int n, int* __restrict__ adj) {
    int i = blockIdx.x * 256 + threadIdx.x;
    if (i < n) adj[row_ptr[i]] = i;
}

// convert chist to absolute cursors: cursor[b][c][j] = row_ptr[node]+1 + prefix(c)
__global__ void k_nscan(int* __restrict__ chist, const int* __restrict__ row_ptr, int n) {
    int i = blockIdx.x * 256 + threadIdx.x;
    if (i >= n) return;
    int b = i >> BSHIFT, j = i & 4095;
    int* p = chist + ((size_t)b * CH) * 4096 + j;
    int s = row_ptr[i] + 1;  // slot 0 = self-loop
#pragma unroll
    for (int c = 0; c < CH; c++) { int t = p[c * 4096]; p[c * 4096] = s; s += t; }
}

// final placement: LDS cursor window, zero global atomics; adj window L2-hot per XCD
__global__ __launch_bounds__(512)
void k_place2(const int2* __restrict__ pairs, const int* __restrict__ gh, int nblk,
              int nb, int E, const int* __restrict__ chist, int* __restrict__ adj) {
    __shared__ int cur[4096];
    int b, c; bc_map(blockIdx.x, &b, &c);
    if (b >= nb) return;
    const int* cs = chist + ((size_t)b * CH + c) * 4096;
    for (int i = threadIdx.x; i < 4096; i += 512) cur[i] = cs[i];
    __syncthreads();
    int estart = gh[b * nblk];
    int eend = (b + 1 < nb) ? gh[(b + 1) * nblk] : E;
    int s0 = estart + c * ECH2;
    int s1 = min(s0 + ECH2, eend);
    for (int i = s0 + threadIdx.x; i < s1; i += 512) {
        int2 p = pairs[i];
        int pos = atomicAdd(&cur[p.y & 4095], 1);
        adj[pos] = p.x;
    }
}

// ---------------- GEMM1: h1 = x @ W1 ----------------
// lane = row (coalesced x loads); block-uniform column half -> W1 via SGPR loads.

__global__ __launch_bounds__(256, 4)
void k_gemm1(const float* __restrict__ x, const float* __restrict__ W1,
             float* __restrict__ h1, int n) {
    int t = threadIdx.x;
    int wave = t >> 6, lane = t & 63;
    int chalf = (blockIdx.x & 1) * 32;                  // block-uniform column half
    int row = (blockIdx.x >> 1) * 256 + wave * 64 + lane;
    bool active = row < n;
    int rowc = active ? row : n - 1;
    const float4* xr = (const float4*)(x + (size_t)rowc * IN_DIM);

    float acc[32];
#pragma unroll
    for (int c = 0; c < 32; c++) acc[c] = 0.f;

#define FMA_K(XC, KK) { \
        const float* wk = wb + (KK) * C1; \
        _Pragma("unroll") \
        for (int c = 0; c < 32; c++) acc[c] = fmaf((XC), wk[c], acc[c]); }

    for (int k0 = 0; k0 < 16; k0++) {                   // BK = 16
        float4 xv0 = xr[k0 * 4 + 0];
        float4 xv1 = xr[k0 * 4 + 1];
        float4 xv2 = xr[k0 * 4 + 2];
        float4 xv3 = xr[k0 * 4 + 3];
        const float* wb = W1 + (size_t)(k0 * 16) * C1 + chalf;  // uniform
        FMA_K(xv0.x, 0)  FMA_K(xv0.y, 1)  FMA_K(xv0.z, 2)  FMA_K(xv0.w, 3)
        FMA_K(xv1.x, 4)  FMA_K(xv1.y, 5)  FMA_K(xv1.z, 6)  FMA_K(xv1.w, 7)
        FMA_K(xv2.x, 8)  FMA_K(xv2.y, 9)  FMA_K(xv2.z, 10) FMA_K(xv2.w, 11)
        FMA_K(xv3.x, 12) FMA_K(xv3.y, 13) FMA_K(xv3.z, 14) FMA_K(xv3.w, 15)
    }
#undef FMA_K

    if (!active) return;
    float* hp = h1 + (size_t)row * C1 + chalf;
#pragma unroll
    for (int j = 0; j < 8; j++)
        *(float4*)(hp + j * 4) =
            make_float4(acc[j * 4], acc[j * 4 + 1], acc[j * 4 + 2], acc[j * 4 + 3]);
}

// ---------------- alpha_src / alpha_dst for layer 1 (wave per row) ----------------

__global__ __launch_bounds__(256)
void k_alpha(const float* __restrict__ h, const float* __restrict__ attS,
             const float* __restrict__ attD, float* __restrict__ as_,
             float* __restrict__ ad_, int n) {
    int wave = (blockIdx.x * 256 + threadIdx.x) >> 6;
    int lane = threadIdx.x & 63;
    if (wave >= n) return;
    float hv = h[(size_t)wave * C1 + lane];
    float vs = hv * attS[lane], vd = hv * attD[lane];
#pragma unroll
    for (int off = 32; off > 0; off >>= 1) {
        vs += __shfl_xor(vs, off);
        vd += __shfl_xor(vd, off);
    }
    if (lane == 0) { as_[wave] = vs; ad_[wave] = vd; }
}

// ---------------- Layer-1 aggregation: one wave per dst node, lane = channel ----------------

__global__ __launch_bounds__(256)
void k_agg1(const float* __restrict__ h1, const float* __restrict__ as1,
            const float* __restrict__ ad1, const int* __restrict__ row_ptr,
            const int* __restrict__ adj, const float* __restrict__ b1,
            float* __restrict__ h1out, int n) {
    int wave = (blockIdx.x * 256 + threadIdx.x) >> 6;
    int lane = threadIdx.x & 63;
    if (wave >= n) return;
    int d = wave;
    int beg = row_ptr[d], end = row_ptr[d + 1];
    float adv = ad1[d];
    float acc = 0.f, dsum = 0.f;
    for (int base = beg; base < end; base += 64) {
        int cnt = min(64, end - base);
        int s = d; float w = 0.f;
        if (lane < cnt) {
            s = adj[base + lane];
            float lg = as1[s] + adv;
            lg = lg > 0.f ? lg : NEG_SLOPE * lg;
            w = expf(lg);
            dsum += w;
        }
        int j = 0;
        for (; j + 4 <= cnt; j += 4) {
            int s0 = __shfl(s, j),     s1 = __shfl(s, j + 1);
            int s2 = __shfl(s, j + 2), s3 = __shfl(s, j + 3);
            float w0 = __shfl(w, j),     w1 = __shfl(w, j + 1);
            float w2 = __shfl(w, j + 2), w3 = __shfl(w, j + 3);
            float g0 = h1[(size_t)s0 * C1 + lane];
            float g1 = h1[(size_t)s1 * C1 + lane];
            float g2 = h1[(size_t)s2 * C1 + lane];
            float g3 = h1[(size_t)s3 * C1 + lane];
            acc = fmaf(w0, g0, acc); acc = fmaf(w1, g1, acc);
            acc = fmaf(w2, g2, acc); acc = fmaf(w3, g3, acc);
        }
        for (; j < cnt; j++) {
            int sj = __shfl(s, j);
            float wj = __shfl(w, j);
            acc = fmaf(wj, h1[(size_t)sj * C1 + lane], acc);
        }
    }
#pragma unroll
    for (int off = 32; off > 0; off >>= 1) dsum += __shfl_xor(dsum, off);
    float out = acc / dsum + b1[lane];
    h1out[(size_t)d * C1 + lane] = out > 0.f ? out : 0.f;
}

// ---------------- GEMM2 + alpha2 ----------------

__global__ __launch_bounds__(256)
void k_gemm2(const float* __restrict__ h1out, const float* __restrict__ W2,
             const float* __restrict__ attS, const float* __restrict__ attD,
             float* __restrict__ h2, float* __restrict__ as2, float* __restrict__ ad2, int n) {
    __shared__ float w2t[C2 * 68];
    __shared__ float sAttS[C2], sAttD[C2];
    int t = threadIdx.x;
    for (int i = t; i < C1 * C2; i += 256) {
        int k = i >> 5, c = i & 31;
        w2t[c * 68 + k] = W2[i];
    }
    if (t < C2) { sAttS[t] = attS[t]; sAttD[t] = attD[t]; }
    __syncthreads();
    int wave = t >> 6, lane = t & 63;
    int col = lane & 31, half = lane >> 5;
    int rowbase = blockIdx.x * 32 + wave * 8;
    const float* wrow = &w2t[col * 68];
    for (int rr = 0; rr < 8; rr += 2) {
        int row = rowbase + rr + half;
        if (row >= n) return;
        float acc = 0.f;
#pragma unroll
        for (int k = 0; k < C1; k += 4) {
            float4 wv = *(const float4*)&wrow[k];
            float4 xv = *(const float4*)&h1out[(size_t)row * C1 + k];
            acc = fmaf(xv.x, wv.x, acc);
            acc = fmaf(xv.y, wv.y, acc);
            acc = fmaf(xv.z, wv.z, acc);
            acc = fmaf(xv.w, wv.w, acc);
        }
        h2[(size_t)row * C2 + col] = acc;
        float vs = acc * sAttS[col], vd = acc * sAttD[col];
#pragma unroll
        for (int off = 16; off > 0; off >>= 1) {
            vs += __shfl_xor(vs, off);
            vd += __shfl_xor(vd, off);
        }
        if (col == 0) { as2[row] = vs; ad2[row] = vd; }
    }
}

// ---------------- Layer-2 aggregation + bias + relu -> emb (d_out) ----------------

__global__ __launch_bounds__(256)
void k_agg2(const float* __restrict__ h2, const float* __restrict__ as2,
            const float* __restrict__ ad2, const int* __restrict__ row_ptr,
            const int* __restrict__ adj, const float* __restrict__ b2,
            float* __restrict__ emb, int n) {
    int wave = (blockIdx.x * 256 + threadIdx.x) >> 6;
    int lane = threadIdx.x & 63;
    if (wave >= n) return;
    int d = wave;
    int beg = row_ptr[d], end = row_ptr[d + 1];
    float adv = ad2[d];
    int c = lane & 31, half = lane >> 5;
    float acc = 0.f, dsum = 0.f;
    for (int base = beg; base < end; base += 64) {
        int cnt = min(64, end - base);
        int s = d; float w = 0.f;
        if (lane < cnt) {
            s = adj[base + lane];
            float lg = as2[s] + adv;
            lg = lg > 0.f ? lg : NEG_SLOPE * lg;
            w = expf(lg);
            dsum += w;
        }
        int j = 0;
        for (; j + 4 <= cnt; j += 4) {
            int sa = __shfl(s, j + half);
            int sb = __shfl(s, j + 2 + half);
            float wa = __shfl(w, j + half);
            float wb = __shfl(w, j + 2 + half);
            float ga = h2[(size_t)sa * C2 + c];
            float gb = h2[(size_t)sb * C2 + c];
            acc = fmaf(wa, ga, acc);
            acc = fmaf(wb, gb, acc);
        }
        for (; j + 2 <= cnt; j += 2) {
            int sj = __shfl(s, j + half);
            float wj = __shfl(w, j + half);
            acc = fmaf(wj, h2[(size_t)sj * C2 + c], acc);
        }
        if (j < cnt) {  // single leftover edge: half 0 only
            int sj = __shfl(s, j);
            float wj = __shfl(w, j);
            if (half == 0) acc = fmaf(wj, h2[(size_t)sj * C2 + c], acc);
        }
    }
    acc += __shfl_xor(acc, 32);
#pragma unroll
    for (int off = 32; off > 0; off >>= 1) dsum += __shfl_xor(dsum, off);
    if (half == 0) {
        float v = acc / dsum + b2[c];
        emb[(size_t)d * C2 + c] = v > 0.f ? v : 0.f;
    }
}

// ---------------- logits = emb @ fcW + fcb ----------------

__global__ __launch_bounds__(256)
void k_logits(const float* __restrict__ emb, const float* __restrict__ fcW,
              const float* __restrict__ fcb, float* __restrict__ out, int n) {
    __shared__ float w[C2 * ODIM];
    __shared__ float b[ODIM];
    int t = threadIdx.x;
    for (int i = t; i < C2 * ODIM; i += 256) w[i] = fcW[i];
    if (t < ODIM) b[t] = fcb[t];
    __syncthreads();
    int lane = t & 63;
    int row = blockIdx.x * 4 + (t >> 6);
    if (row >= n) return;
    float acc = (lane < ODIM) ? b[lane] : 0.f;
    const float4* er = (const float4*)&emb[(size_t)row * C2];
#pragma unroll
    for (int c4 = 0; c4 < 8; c4++) {
        float4 e = er[c4];
        int c = c4 * 4;
        if (lane < ODIM) {
            acc = fmaf(e.x, w[(c + 0) * ODIM + lane], acc);
            acc = fmaf(e.y, w[(c + 1) * ODIM + lane], acc);
            acc = fmaf(e.z, w[(c + 2) * ODIM + lane], acc);
            acc = fmaf(e.w, w[(c + 3) * ODIM + lane], acc);
        }
    }
    if (lane < ODIM) out[(size_t)row * ODIM + lane] = acc;
}

// ---------------- launch ----------------

extern "C" void kernel_launch(void* const* d_in, const int* in_sizes, int n_in,
                              void* d_out, int out_size, void* d_ws, size_t ws_size,
                              hipStream_t stream) {
    const float* x    = (const float*)d_in[0];
    const int*   ei   = (const int*)d_in[1];
    const float* W1   = (const float*)d_in[2];
    const float* aS1  = (const float*)d_in[3];
    const float* aD1  = (const float*)d_in[4];
    const float* b1   = (const float*)d_in[5];
    const float* W2   = (const float*)d_in[6];
    const float* aS2  = (const float*)d_in[7];
    const float* aD2  = (const float*)d_in[8];
    const float* b2   = (const float*)d_in[9];
    const float* fcW  = (const float*)d_in[10];
    const float* fcb  = (const float*)d_in[11];

    const int N = in_sizes[0] / IN_DIM;
    const int E = in_sizes[1] / 2;
    const int* src = ei;
    const int* dst = ei + E;

    // workspace layout
    float* h1    = (float*)d_ws;               // N*64 floats (pre-gemm1: first 4.1MB = chist)
    float* h1out = h1 + (size_t)N * C1;        // N*64 floats (pre-agg1: pairs int2[E])
    float* as1   = h1out + (size_t)N * C1;     // N
    float* ad1   = as1 + N;
    float* as2   = ad1 + N;
    float* ad2   = as2 + N;
    int*   cnt   = (int*)(ad2 + N);            // N
    int*   row_ptr = cnt + N;                  // N+1
    int*   bsums   = row_ptr + (N + 1);        // <=256
    int*   adj     = bsums + 256;              // E+N
    int*   gh      = adj + (E + N);            // nb*nblkE (~10K)
    float* h2    = h1;                         // alias: h1 dead after k_agg1

    int2* pairs = (int2*)h1out;                // E int2 == N*64 floats exactly
    int*  chist = (int*)h1;                    // nb*CH*4096 ints (4.1MB) << N*64 floats

    float* emb    = (float*)d_out;             // N*32
    float* logits = emb + (size_t)N * C2;      // N*40

    int nbN   = (N + 255) / 256;
    int nbS   = (N + SCAN_CHUNK - 1) / SCAN_CHUNK;  // 25
    int nblkE = (E + ECHUNK - 1) / ECHUNK;          // ~391
    int nb    = (N + (1 << BSHIFT) - 1) >> BSHIFT;  // ~25 buckets (must be <= 32)
    int nBC   = 8 * 4 * CH;                         // (xcd, b-slot, chunk) blocks

    // CSR build — no per-edge global atomics anywhere
    k_bhist<<<nblkE, 256, 0, stream>>>(dst, E, gh, nblkE, nb);
    k_bscan<<<1, 256, 0, stream>>>(gh, nb * nblkE);
    k_bplace<<<nblkE, 256, 0, stream>>>(src, dst, E, gh, nblkE, nb, pairs);
    k_nhist<<<nBC, 512, 0, stream>>>(pairs, gh, nblkE, nb, E, chist);
    k_cnt<<<nbN, 256, 0, stream>>>(chist, cnt, N);
    k_scan1<<<nbS, 256, 0, stream>>>(cnt, N, bsums);
    k_scan2<<<1, 256, 0, stream>>>(bsums, nbS, row_ptr, N, E + N);
    k_scan3<<<nbS, 256, 0, stream>>>(cnt, N, bsums, row_ptr);
    k_selfloop<<<nbN, 256, 0, stream>>>(row_ptr, N, adj);
    k_nscan<<<nbN, 256, 0, stream>>>(chist, row_ptr, N);
    k_place2<<<nBC, 512, 0, stream>>>(pairs, gh, nblkE, nb, E, chist, adj);

    // GAT layers
    int nbG1 = 2 * ((N + 255) / 256);   // x2: column halves
    k_gemm1<<<nbG1, 256, 0, stream>>>(x, W1, h1, N);
    int nbA = (N + 3) / 4;
    k_alpha<<<nbA, 256, 0, stream>>>(h1, aS1, aD1, as1, ad1, N);
    k_agg1<<<nbA, 256, 0, stream>>>(h1, as1, ad1, row_ptr, adj, b1, h1out, N);
    int nbG2 = (N + 31) / 32;
    k_gemm2<<<nbG2, 256, 0, stream>>>(h1out, W2, aS2, aD2, h2, as2, ad2, N);
    k_agg2<<<nbA, 256, 0, stream>>>(h2, as2, ad2, row_ptr, adj, b2, emb, N);
    k_logits<<<nbA, 256, 0, stream>>>(emb, fcW, fcb, logits, N);
}

// Round 10
// 447.514 us; speedup vs baseline: 1.6294x; 1.0495x over previous
//
#include <hip/hip_runtime.h>
#include <hip/hip_bf16.h>

#define NEG_SLOPE 0.2f
#define IN_DIM 256
#define C1 64
#define C2 32
#define ODIM 40
#define SCAN_CHUNK 4096   // 256 threads * 16 items
#define BSHIFT 12         // bucket = dst >> 12 (4096 nodes/bucket)
#define ECHUNK 8192       // edges per block in bucket passes
#define ECH2 16384        // edges per (bucket,chunk) block in node passes
#define CH 10             // max chunks per bucket (131K avg edges/bucket << CH*ECH2)

// ---------------- CSR build: bucket sort, then in-bucket counting sort ----------------

// per-block bucket histogram -> gh[bucket][block]
__global__ void k_bhist(const int* __restrict__ dst, int E, int* __restrict__ gh,
                        int nblk, int nb) {
    __shared__ int h[32];
    int t = threadIdx.x;
    if (t < 32) h[t] = 0;
    __syncthreads();
    int base = blockIdx.x * ECHUNK;
    int end = min(base + ECHUNK, E);
    for (int i = base + t; i < end; i += 256) atomicAdd(&h[dst[i] >> BSHIFT], 1);
    __syncthreads();
    if (t < nb) gh[t * nblk + blockIdx.x] = h[t];
}

// flat exclusive scan of gh (bucket-major), single block
__global__ void k_bscan(int* __restrict__ gh, int L) {
    __shared__ int lds[256];
    __shared__ int carry;
    int t = threadIdx.x;
    if (t == 0) carry = 0;
    __syncthreads();
    for (int base = 0; base < L; base += 256) {
        int v = (base + t < L) ? gh[base + t] : 0;
        lds[t] = v; __syncthreads();
        for (int off = 1; off < 256; off <<= 1) {
            int u = (t >= off) ? lds[t - off] : 0;
            __syncthreads();
            lds[t] += u;
            __syncthreads();
        }
        if (base + t < L) gh[base + t] = lds[t] - v + carry;  // exclusive + carry
        __syncthreads();
        if (t == 0) carry += lds[255];
        __syncthreads();
    }
}

// place edges into bucket-ordered int2 pairs (LDS cursors, no global atomics)
__global__ void k_bplace(const int* __restrict__ src, const int* __restrict__ dst, int E,
                         const int* __restrict__ gh, int nblk, int nb,
                         int2* __restrict__ pairs) {
    __shared__ int cur[32];
    int t = threadIdx.x;
    if (t < nb) cur[t] = gh[t * nblk + blockIdx.x];
    __syncthreads();
    int base = blockIdx.x * ECHUNK;
    int end = min(base + ECHUNK, E);
    for (int i = base + t; i < end; i += 256) {
        int d = dst[i];
        int pos = atomicAdd(&cur[d >> BSHIFT], 1);
        pairs[pos] = make_int2(src[i], d);
    }
}

// block -> (bucket, chunk): xcd-pinned (b & 7 == blockIdx % 8) for L2 locality
__device__ __forceinline__ void bc_map(int blk, int* b, int* c) {
    int xcd = blk & 7, k = blk >> 3;
    *b = (k & 3) * 8 + xcd;
    *c = k >> 2;
}

// per-(bucket,chunk) node-level LDS histogram -> chist[b][c][4096]
__global__ __launch_bounds__(512)
void k_nhist(const int2* __restrict__ pairs, const int* __restrict__ gh, int nblk,
             int nb, int E, int* __restrict__ chist) {
    __shared__ int h[4096];
    int b, c; bc_map(blockIdx.x, &b, &c);
    if (b >= nb) return;
    for (int i = threadIdx.x; i < 4096; i += 512) h[i] = 0;
    __syncthreads();
    int estart = gh[b * nblk];
    int eend = (b + 1 < nb) ? gh[(b + 1) * nblk] : E;
    int s0 = estart + c * ECH2;
    int s1 = min(s0 + ECH2, eend);
    for (int i = s0 + threadIdx.x; i < s1; i += 512)
        atomicAdd(&h[pairs[i].y & 4095], 1);
    __syncthreads();
    int* out = chist + ((size_t)b * CH + c) * 4096;
    for (int i = threadIdx.x; i < 4096; i += 512) out[i] = h[i];
}

// cnt[i] = 1 (self-loop) + sum over chunks; coalesced, no atomics
__global__ void k_cnt(const int* __restrict__ chist, int* __restrict__ cnt, int n) {
    int i = blockIdx.x * 256 + threadIdx.x;
    if (i >= n) return;
    int b = i >> BSHIFT, j = i & 4095;
    const int* p = chist + ((size_t)b * CH) * 4096 + j;
    int s = 1;
#pragma unroll
    for (int c = 0; c < CH; c++) s += p[c * 4096];
    cnt[i] = s;
}

__global__ void k_scan1(const int* __restrict__ cnt, int n, int* __restrict__ bsums) {
    __shared__ int lds[256];
    int t = threadIdx.x;
    int base = blockIdx.x * SCAN_CHUNK + t * 16;
    int s = 0;
#pragma unroll
    for (int i = 0; i < 16; i++) { int idx = base + i; s += (idx < n) ? cnt[idx] : 0; }
    lds[t] = s; __syncthreads();
    for (int off = 128; off > 0; off >>= 1) {
        if (t < off) lds[t] += lds[t + off];
        __syncthreads();
    }
    if (t == 0) bsums[blockIdx.x] = lds[0];
}

__global__ void k_scan2(int* bsums, int nb, int* row_ptr, int n, int total) {
    __shared__ int lds[256];
    int t = threadIdx.x;
    int v = (t < nb) ? bsums[t] : 0;
    lds[t] = v; __syncthreads();
    for (int off = 1; off < 256; off <<= 1) {
        int u = (t >= off) ? lds[t - off] : 0;
        __syncthreads();
        lds[t] += u;
        __syncthreads();
    }
    if (t < nb) bsums[t] = lds[t] - v;  // exclusive
    if (t == 0) row_ptr[n] = total;
}

__global__ void k_scan3(const int* __restrict__ cnt, int n, const int* __restrict__ bsums,
                        int* __restrict__ row_ptr) {
    __shared__ int lds[256];
    int t = threadIdx.x;
    int base = blockIdx.x * SCAN_CHUNK + t * 16;
    int loc[16];
    int s = 0;
#pragma unroll
    for (int i = 0; i < 16; i++) {
        int idx = base + i;
        int c = (idx < n) ? cnt[idx] : 0;
        loc[i] = s; s += c;
    }
    lds[t] = s; __syncthreads();
    for (int off = 1; off < 256; off <<= 1) {
        int u = (t >= off) ? lds[t - off] : 0;
        __syncthreads();
        lds[t] += u;
        __syncthreads();
    }
    int texcl = lds[t] - s + bsums[blockIdx.x];
#pragma unroll
    for (int i = 0; i < 16; i++) {
        int idx = base + i;
        if (idx < n) row_ptr[idx] = texcl + loc[i];
    }
}

__global__ void k_selfloop(const int* __restrict__ row_ptr, int n, int* __restrict__ adj) {
    int i = blockIdx.x * 256 + threadIdx.x;
    if (i < n) adj[row_ptr[i]] = i;
}

// convert chist to absolute cursors: cursor[b][c][j] = row_ptr[node]+1 + prefix(c)
__global__ void k_nscan(int* __restrict__ chist, const int* __restrict__ row_ptr, int n) {
    int i = blockIdx.x * 256 + threadIdx.x;
    if (i >= n) return;
    int b = i >> BSHIFT, j = i & 4095;
    int* p = chist + ((size_t)b * CH) * 4096 + j;
    int s = row_ptr[i] + 1;  // slot 0 = self-loop
#pragma unroll
    for (int c = 0; c < CH; c++) { int t = p[c * 4096]; p[c * 4096] = s; s += t; }
}

// final placement: LDS cursor window, zero global atomics; adj window L2-hot per XCD
__global__ __launch_bounds__(512)
void k_place2(const int2* __restrict__ pairs, const int* __restrict__ gh, int nblk,
              int nb, int E, const int* __restrict__ chist, int* __restrict__ adj) {
    __shared__ int cur[4096];
    int b, c; bc_map(blockIdx.x, &b, &c);
    if (b >= nb) return;
    const int* cs = chist + ((size_t)b * CH + c) * 4096;
    for (int i = threadIdx.x; i < 4096; i += 512) cur[i] = cs[i];
    __syncthreads();
    int estart = gh[b * nblk];
    int eend = (b + 1 < nb) ? gh[(b + 1) * nblk] : E;
    int s0 = estart + c * ECH2;
    int s1 = min(s0 + ECH2, eend);
    for (int i = s0 + threadIdx.x; i < s1; i += 512) {
        int2 p = pairs[i];
        int pos = atomicAdd(&cur[p.y & 4095], 1);
        adj[pos] = p.x;
    }
}

// ---------------- GEMM1: h1 = x @ W1 ----------------
// lane = row (coalesced x loads); block-uniform column half -> W1 via SGPR loads.

__global__ __launch_bounds__(256, 4)
void k_gemm1(const float* __restrict__ x, const float* __restrict__ W1,
             float* __restrict__ h1, int n) {
    int t = threadIdx.x;
    int wave = t >> 6, lane = t & 63;
    int chalf = (blockIdx.x & 1) * 32;                  // block-uniform column half
    int row = (blockIdx.x >> 1) * 256 + wave * 64 + lane;
    bool active = row < n;
    int rowc = active ? row : n - 1;
    const float4* xr = (const float4*)(x + (size_t)rowc * IN_DIM);

    float acc[32];
#pragma unroll
    for (int c = 0; c < 32; c++) acc[c] = 0.f;

#define FMA_K(XC, KK) { \
        const float* wk = wb + (KK) * C1; \
        _Pragma("unroll") \
        for (int c = 0; c < 32; c++) acc[c] = fmaf((XC), wk[c], acc[c]); }

    for (int k0 = 0; k0 < 16; k0++) {                   // BK = 16
        float4 xv0 = xr[k0 * 4 + 0];
        float4 xv1 = xr[k0 * 4 + 1];
        float4 xv2 = xr[k0 * 4 + 2];
        float4 xv3 = xr[k0 * 4 + 3];
        const float* wb = W1 + (size_t)(k0 * 16) * C1 + chalf;  // uniform
        FMA_K(xv0.x, 0)  FMA_K(xv0.y, 1)  FMA_K(xv0.z, 2)  FMA_K(xv0.w, 3)
        FMA_K(xv1.x, 4)  FMA_K(xv1.y, 5)  FMA_K(xv1.z, 6)  FMA_K(xv1.w, 7)
        FMA_K(xv2.x, 8)  FMA_K(xv2.y, 9)  FMA_K(xv2.z, 10) FMA_K(xv2.w, 11)
        FMA_K(xv3.x, 12) FMA_K(xv3.y, 13) FMA_K(xv3.z, 14) FMA_K(xv3.w, 15)
    }
#undef FMA_K

    if (!active) return;
    float* hp = h1 + (size_t)row * C1 + chalf;
#pragma unroll
    for (int j = 0; j < 8; j++)
        *(float4*)(hp + j * 4) =
            make_float4(acc[j * 4], acc[j * 4 + 1], acc[j * 4 + 2], acc[j * 4 + 3]);
}

// ---------------- alpha_src / alpha_dst for layer 1 (wave per row) ----------------

__global__ __launch_bounds__(256)
void k_alpha(const float* __restrict__ h, const float* __restrict__ attS,
             const float* __restrict__ attD, float* __restrict__ as_,
             float* __restrict__ ad_, int n) {
    int wave = (blockIdx.x * 256 + threadIdx.x) >> 6;
    int lane = threadIdx.x & 63;
    if (wave >= n) return;
    float hv = h[(size_t)wave * C1 + lane];
    float vs = hv * attS[lane], vd = hv * attD[lane];
#pragma unroll
    for (int off = 32; off > 0; off >>= 1) {
        vs += __shfl_xor(vs, off);
        vd += __shfl_xor(vd, off);
    }
    if (lane == 0) { as_[wave] = vs; ad_[wave] = vd; }
}

// ---------------- Layer-1 aggregation ----------------
// one wave per dst node; lane -> (edge-group g=lane>>4, float4-chunk cq=lane&15):
// one global_load_dwordx4 fetches 4 edges' rows (1KB) per instruction.
// lanes >= deg carry w=0, s=d -> overrun slots are inert (weight-0 fma, cached row).

__global__ __launch_bounds__(256)
void k_agg1(const float* __restrict__ h1, const float* __restrict__ as1,
            const float* __restrict__ ad1, const int* __restrict__ row_ptr,
            const int* __restrict__ adj, const float* __restrict__ b1,
            float* __restrict__ h1out, int n) {
    int wave = (blockIdx.x * 256 + threadIdx.x) >> 6;
    int lane = threadIdx.x & 63;
    if (wave >= n) return;
    int d = wave;
    int beg = row_ptr[d], end = row_ptr[d + 1];
    float adv = ad1[d];
    int g = lane >> 4;      // edge slot within group-of-4
    int cq = lane & 15;     // float4 index within 64-col row
    float4 acc = make_float4(0.f, 0.f, 0.f, 0.f);
    float dsum = 0.f;
    for (int base = beg; base < end; base += 64) {
        int cnt = min(64, end - base);
        int s = d; float w = 0.f;
        if (lane < cnt) {
            s = adj[base + lane];
            float lg = as1[s] + adv;
            lg = lg > 0.f ? lg : NEG_SLOPE * lg;
            w = expf(lg);
            dsum += w;
        }
        int j = 0;
        for (; j + 16 <= cnt; j += 16) {      // 16 edges: 4 rounds of 4 (4 loads in flight)
#pragma unroll
            for (int r = 0; r < 4; r++) {
                int e = j + r * 4 + g;
                int se = __shfl(s, e);
                float we = __shfl(w, e);
                float4 hv = ((const float4*)(h1 + (size_t)se * C1))[cq];
                acc.x = fmaf(we, hv.x, acc.x);
                acc.y = fmaf(we, hv.y, acc.y);
                acc.z = fmaf(we, hv.z, acc.z);
                acc.w = fmaf(we, hv.w, acc.w);
            }
        }
        for (; j < cnt; j += 4) {             // tail rounds (<= 3 wasted slots)
            int e = j + g;
            int se = __shfl(s, e);
            float we = __shfl(w, e);
            float4 hv = ((const float4*)(h1 + (size_t)se * C1))[cq];
            acc.x = fmaf(we, hv.x, acc.x);
            acc.y = fmaf(we, hv.y, acc.y);
            acc.z = fmaf(we, hv.z, acc.z);
            acc.w = fmaf(we, hv.w, acc.w);
        }
    }
#pragma unroll
    for (int off = 32; off > 0; off >>= 1) dsum += __shfl_xor(dsum, off);
#pragma unroll
    for (int off = 16; off <= 32; off <<= 1) {  // fold the 4 edge-groups
        acc.x += __shfl_xor(acc.x, off);
        acc.y += __shfl_xor(acc.y, off);
        acc.z += __shfl_xor(acc.z, off);
        acc.w += __shfl_xor(acc.w, off);
    }
    if (g == 0) {
        float inv = 1.f / dsum;
        float4 bv = ((const float4*)b1)[cq];
        float4 o;
        o.x = acc.x * inv + bv.x; o.x = o.x > 0.f ? o.x : 0.f;
        o.y = acc.y * inv + bv.y; o.y = o.y > 0.f ? o.y : 0.f;
        o.z = acc.z * inv + bv.z; o.z = o.z > 0.f ? o.z : 0.f;
        o.w = acc.w * inv + bv.w; o.w = o.w > 0.f ? o.w : 0.f;
        ((float4*)(h1out + (size_t)d * C1))[cq] = o;
    }
}

// ---------------- GEMM2 + alpha2 ----------------

__global__ __launch_bounds__(256)
void k_gemm2(const float* __restrict__ h1out, const float* __restrict__ W2,
             const float* __restrict__ attS, const float* __restrict__ attD,
             float* __restrict__ h2, float* __restrict__ as2, float* __restrict__ ad2, int n) {
    __shared__ float w2t[C2 * 68];
    __shared__ float sAttS[C2], sAttD[C2];
    int t = threadIdx.x;
    for (int i = t; i < C1 * C2; i += 256) {
        int k = i >> 5, c = i & 31;
        w2t[c * 68 + k] = W2[i];
    }
    if (t < C2) { sAttS[t] = attS[t]; sAttD[t] = attD[t]; }
    __syncthreads();
    int wave = t >> 6, lane = t & 63;
    int col = lane & 31, half = lane >> 5;
    int rowbase = blockIdx.x * 32 + wave * 8;
    const float* wrow = &w2t[col * 68];
    for (int rr = 0; rr < 8; rr += 2) {
        int row = rowbase + rr + half;
        if (row >= n) return;
        float acc = 0.f;
#pragma unroll
        for (int k = 0; k < C1; k += 4) {
            float4 wv = *(const float4*)&wrow[k];
            float4 xv = *(const float4*)&h1out[(size_t)row * C1 + k];
            acc = fmaf(xv.x, wv.x, acc);
            acc = fmaf(xv.y, wv.y, acc);
            acc = fmaf(xv.z, wv.z, acc);
            acc = fmaf(xv.w, wv.w, acc);
        }
        h2[(size_t)row * C2 + col] = acc;
        float vs = acc * sAttS[col], vd = acc * sAttD[col];
#pragma unroll
        for (int off = 16; off > 0; off >>= 1) {
            vs += __shfl_xor(vs, off);
            vd += __shfl_xor(vd, off);
        }
        if (col == 0) { as2[row] = vs; ad2[row] = vd; }
    }
}

// ---------------- Layer-2 aggregation + bias + relu -> emb ----------------
// same structure as agg1: 8 edge-groups (g=lane>>3), float4 chunk cq=lane&7.

__global__ __launch_bounds__(256)
void k_agg2(const float* __restrict__ h2, const float* __restrict__ as2,
            const float* __restrict__ ad2, const int* __restrict__ row_ptr,
            const int* __restrict__ adj, const float* __restrict__ b2,
            float* __restrict__ emb, int n) {
    int wave = (blockIdx.x * 256 + threadIdx.x) >> 6;
    int lane = threadIdx.x & 63;
    if (wave >= n) return;
    int d = wave;
    int beg = row_ptr[d], end = row_ptr[d + 1];
    float adv = ad2[d];
    int g = lane >> 3;      // edge slot within group-of-8
    int cq = lane & 7;      // float4 index within 32-col row
    float4 acc = make_float4(0.f, 0.f, 0.f, 0.f);
    float dsum = 0.f;
    for (int base = beg; base < end; base += 64) {
        int cnt = min(64, end - base);
        int s = d; float w = 0.f;
        if (lane < cnt) {
            s = adj[base + lane];
            float lg = as2[s] + adv;
            lg = lg > 0.f ? lg : NEG_SLOPE * lg;
            w = expf(lg);
            dsum += w;
        }
        int j = 0;
        for (; j + 32 <= cnt; j += 32) {      // 32 edges: 4 rounds of 8
#pragma unroll
            for (int r = 0; r < 4; r++) {
                int e = j + r * 8 + g;
                int se = __shfl(s, e);
                float we = __shfl(w, e);
                float4 hv = ((const float4*)(h2 + (size_t)se * C2))[cq];
                acc.x = fmaf(we, hv.x, acc.x);
                acc.y = fmaf(we, hv.y, acc.y);
                acc.z = fmaf(we, hv.z, acc.z);
                acc.w = fmaf(we, hv.w, acc.w);
            }
        }
        for (; j < cnt; j += 8) {             // tail rounds
            int e = j + g;
            int se = __shfl(s, e);
            float we = __shfl(w, e);
            float4 hv = ((const float4*)(h2 + (size_t)se * C2))[cq];
            acc.x = fmaf(we, hv.x, acc.x);
            acc.y = fmaf(we, hv.y, acc.y);
            acc.z = fmaf(we, hv.z, acc.z);
            acc.w = fmaf(we, hv.w, acc.w);
        }
    }
#pragma unroll
    for (int off = 32; off > 0; off >>= 1) dsum += __shfl_xor(dsum, off);
#pragma unroll
    for (int off = 8; off <= 32; off <<= 1) {  // fold the 8 edge-groups
        acc.x += __shfl_xor(acc.x, off);
        acc.y += __shfl_xor(acc.y, off);
        acc.z += __shfl_xor(acc.z, off);
        acc.w += __shfl_xor(acc.w, off);
    }
    if (g == 0) {
        float inv = 1.f / dsum;
        float4 bv = ((const float4*)b2)[cq];
        float4 o;
        o.x = acc.x * inv + bv.x; o.x = o.x > 0.f ? o.x : 0.f;
        o.y = acc.y * inv + bv.y; o.y = o.y > 0.f ? o.y : 0.f;
        o.z = acc.z * inv + bv.z; o.z = o.z > 0.f ? o.z : 0.f;
        o.w = acc.w * inv + bv.w; o.w = o.w > 0.f ? o.w : 0.f;
        ((float4*)(emb + (size_t)d * C2))[cq] = o;
    }
}

// ---------------- logits = emb @ fcW + fcb ----------------

__global__ __launch_bounds__(256)
void k_logits(const float* __restrict__ emb, const float* __restrict__ fcW,
              const float* __restrict__ fcb, float* __restrict__ out, int n) {
    __shared__ float w[C2 * ODIM];
    __shared__ float b[ODIM];
    int t = threadIdx.x;
    for (int i = t; i < C2 * ODIM; i += 256) w[i] = fcW[i];
    if (t < ODIM) b[t] = fcb[t];
    __syncthreads();
    int lane = t & 63;
    int row = blockIdx.x * 4 + (t >> 6);
    if (row >= n) return;
    float acc = (lane < ODIM) ? b[lane] : 0.f;
    const float4* er = (const float4*)&emb[(size_t)row * C2];
#pragma unroll
    for (int c4 = 0; c4 < 8; c4++) {
        float4 e = er[c4];
        int c = c4 * 4;
        if (lane < ODIM) {
            acc = fmaf(e.x, w[(c + 0) * ODIM + lane], acc);
            acc = fmaf(e.y, w[(c + 1) * ODIM + lane], acc);
            acc = fmaf(e.z, w[(c + 2) * ODIM + lane], acc);
            acc = fmaf(e.w, w[(c + 3) * ODIM + lane], acc);
        }
    }
    if (lane < ODIM) out[(size_t)row * ODIM + lane] = acc;
}

// ---------------- launch ----------------

extern "C" void kernel_launch(void* const* d_in, const int* in_sizes, int n_in,
                              void* d_out, int out_size, void* d_ws, size_t ws_size,
                              hipStream_t stream) {
    const float* x    = (const float*)d_in[0];
    const int*   ei   = (const int*)d_in[1];
    const float* W1   = (const float*)d_in[2];
    const float* aS1  = (const float*)d_in[3];
    const float* aD1  = (const float*)d_in[4];
    const float* b1   = (const float*)d_in[5];
    const float* W2   = (const float*)d_in[6];
    const float* aS2  = (const float*)d_in[7];
    const float* aD2  = (const float*)d_in[8];
    const float* b2   = (const float*)d_in[9];
    const float* fcW  = (const float*)d_in[10];
    const float* fcb  = (const float*)d_in[11];

    const int N = in_sizes[0] / IN_DIM;
    const int E = in_sizes[1] / 2;
    const int* src = ei;
    const int* dst = ei + E;

    // workspace layout
    float* h1    = (float*)d_ws;               // N*64 floats (pre-gemm1: first 4.1MB = chist)
    float* h1out = h1 + (size_t)N * C1;        // N*64 floats (pre-agg1: pairs int2[E])
    float* as1   = h1out + (size_t)N * C1;     // N
    float* ad1   = as1 + N;
    float* as2   = ad1 + N;
    float* ad2   = as2 + N;
    int*   cnt   = (int*)(ad2 + N);            // N
    int*   row_ptr = cnt + N;                  // N+1
    int*   bsums   = row_ptr + (N + 1);        // <=256
    int*   adj     = bsums + 256;              // E+N
    int*   gh      = adj + (E + N);            // nb*nblkE (~10K)
    float* h2    = h1;                         // alias: h1 dead after k_agg1

    int2* pairs = (int2*)h1out;                // E int2 == N*64 floats exactly
    int*  chist = (int*)h1;                    // nb*CH*4096 ints (4.1MB) << N*64 floats

    float* emb    = (float*)d_out;             // N*32
    float* logits = emb + (size_t)N * C2;      // N*40

    int nbN   = (N + 255) / 256;
    int nbS   = (N + SCAN_CHUNK - 1) / SCAN_CHUNK;  // 25
    int nblkE = (E + ECHUNK - 1) / ECHUNK;          // ~391
    int nb    = (N + (1 << BSHIFT) - 1) >> BSHIFT;  // ~25 buckets (must be <= 32)
    int nBC   = 8 * 4 * CH;                         // (xcd, b-slot, chunk) blocks

    // CSR build — no per-edge global atomics anywhere
    k_bhist<<<nblkE, 256, 0, stream>>>(dst, E, gh, nblkE, nb);
    k_bscan<<<1, 256, 0, stream>>>(gh, nb * nblkE);
    k_bplace<<<nblkE, 256, 0, stream>>>(src, dst, E, gh, nblkE, nb, pairs);
    k_nhist<<<nBC, 512, 0, stream>>>(pairs, gh, nblkE, nb, E, chist);
    k_cnt<<<nbN, 256, 0, stream>>>(chist, cnt, N);
    k_scan1<<<nbS, 256, 0, stream>>>(cnt, N, bsums);
    k_scan2<<<1, 256, 0, stream>>>(bsums, nbS, row_ptr, N, E + N);
    k_scan3<<<nbS, 256, 0, stream>>>(cnt, N, bsums, row_ptr);
    k_selfloop<<<nbN, 256, 0, stream>>>(row_ptr, N, adj);
    k_nscan<<<nbN, 256, 0, stream>>>(chist, row_ptr, N);
    k_place2<<<nBC, 512, 0, stream>>>(pairs, gh, nblkE, nb, E, chist, adj);

    // GAT layers
    int nbG1 = 2 * ((N + 255) / 256);   // x2: column halves
    k_gemm1<<<nbG1, 256, 0, stream>>>(x, W1, h1, N);
    int nbA = (N + 3) / 4;
    k_alpha<<<nbA, 256, 0, stream>>>(h1, aS1, aD1, as1, ad1, N);
    k_agg1<<<nbA, 256, 0, stream>>>(h1, as1, ad1, row_ptr, adj, b1, h1out, N);
    int nbG2 = (N + 31) / 32;
    k_gemm2<<<nbG2, 256, 0, stream>>>(h1out, W2, aS2, aD2, h2, as2, ad2, N);
    k_agg2<<<nbA, 256, 0, stream>>>(h2, as2, ad2, row_ptr, adj, b2, emb, N);
    k_logits<<<nbA, 256, 0, stream>>>(emb, fcW, fcb, logits, N);
}